// Round 1
// baseline (7607.891 us; speedup 1.0000x reference)
//
#include <hip/hip_runtime.h>
#include <math.h>

#define T_N   262144
#define NSTEP (T_N - 1)   // 262143 scan steps
#define CS    256         // chunk size
#define NC    1024        // number of chunks (NC*CS >= NSTEP)
#define NG    32          // groups of chunks (NC/32)

// output layout (floats): log_alpha(T,16) log_beta(T,16) log_trs(T-1,256) log_pis(T,16) entropy(T-1,16)
#define OFF_A   ((size_t)0)
#define OFF_B   ((size_t)4194304)
#define OFF_LTR ((size_t)8388608)
#define OFF_LPI ((size_t)75497216)
#define OFF_ENT ((size_t)79691520)

// workspace layout (floats)
#define WS_TR0  ((size_t)0)
#define WS_M    ((size_t)64)
#define WS_LP   (WS_M  + (size_t)NC*256)
#define WS_LS   (WS_LP + (size_t)NC*256)
#define WS_GT   (WS_LS + (size_t)NC*256)
#define WS_GP   (WS_GT + (size_t)NG*256)
#define WS_GSU  (WS_GP + (size_t)NG*256)
#define WS_PREF (WS_GSU + (size_t)NG*256)
#define WS_SUF  (WS_PREF + (size_t)NC*256)

#define NEGINF (-1e30f)

// ---------------------------------------------------------------- K1: MLPs ---

template<int KD, int LDI>
__device__ __forceinline__ void gemm_16col(const float* X, const float* __restrict__ W,
    int wld, const float* __restrict__ bias, int colb, int rh, float* acc0, float* acc1)
{
#pragma unroll
  for (int j = 0; j < 16; j++) { float bb = bias[colb + j]; acc0[j] = bb; acc1[j] = bb; }
  const float* x0p = X + rh * LDI;
  const float* x1p = X + (rh + 16) * LDI;
  for (int k = 0; k < KD; k++) {
    float x0 = x0p[k], x1 = x1p[k];
    const float* wr = W + (size_t)k * wld + colb;
    float4 wa = *(const float4*)(wr + 0);
    float4 wb = *(const float4*)(wr + 4);
    float4 wc = *(const float4*)(wr + 8);
    float4 wd = *(const float4*)(wr + 12);
    float wv[16] = {wa.x,wa.y,wa.z,wa.w, wb.x,wb.y,wb.z,wb.w,
                    wc.x,wc.y,wc.z,wc.w, wd.x,wd.y,wd.z,wd.w};
#pragma unroll
    for (int j = 0; j < 16; j++) { acc0[j] = fmaf(x0, wv[j], acc0[j]); acc1[j] = fmaf(x1, wv[j], acc1[j]); }
  }
}

template<int KD, int LDI>
__device__ __forceinline__ void gemm_8col(const float* X, const float* __restrict__ W,
    int wld, const float* __restrict__ bias, int colb, int rh, float* acc0, float* acc1)
{
#pragma unroll
  for (int j = 0; j < 8; j++) { float bb = bias[colb + j]; acc0[j] = bb; acc1[j] = bb; }
  const float* x0p = X + rh * LDI;
  const float* x1p = X + (rh + 16) * LDI;
  for (int k = 0; k < KD; k++) {
    float x0 = x0p[k], x1 = x1p[k];
    const float* wr = W + (size_t)k * wld + colb;
    float4 wa = *(const float4*)(wr + 0);
    float4 wb = *(const float4*)(wr + 4);
    float wv[8] = {wa.x,wa.y,wa.z,wa.w, wb.x,wb.y,wb.z,wb.w};
#pragma unroll
    for (int j = 0; j < 8; j++) { acc0[j] = fmaf(x0, wv[j], acc0[j]); acc1[j] = fmaf(x1, wv[j], acc1[j]); }
  }
}

__device__ __forceinline__ void store_relu16(float* Hs, int r, int colb, const float* a)
{
  float* p = Hs + r * 260 + colb;
  *(float4*)(p + 0)  = make_float4(fmaxf(a[0],0.f),  fmaxf(a[1],0.f),  fmaxf(a[2],0.f),  fmaxf(a[3],0.f));
  *(float4*)(p + 4)  = make_float4(fmaxf(a[4],0.f),  fmaxf(a[5],0.f),  fmaxf(a[6],0.f),  fmaxf(a[7],0.f));
  *(float4*)(p + 8)  = make_float4(fmaxf(a[8],0.f),  fmaxf(a[9],0.f),  fmaxf(a[10],0.f), fmaxf(a[11],0.f));
  *(float4*)(p + 12) = make_float4(fmaxf(a[12],0.f), fmaxf(a[13],0.f), fmaxf(a[14],0.f), fmaxf(a[15],0.f));
}

__device__ __forceinline__ void softmax_ep(float* lg, size_t tg, int i, float* out)
{
  float m = NEGINF;
#pragma unroll
  for (int j = 0; j < 16; j++) m = fmaxf(m, lg[j]);
  float s = 0.f;
#pragma unroll
  for (int j = 0; j < 16; j++) s += __expf(lg[j] - m);
  float L = m + __logf(s);
  float ent = 0.f;
#pragma unroll
  for (int j = 0; j < 16; j++) { float v = lg[j] - L; lg[j] = v; ent -= v * __expf(v); }
  if (tg >= 1) {
    float* dst = out + OFF_LTR + (tg - 1) * 256 + i * 16;
    *(float4*)(dst + 0)  = make_float4(lg[0],  lg[1],  lg[2],  lg[3]);
    *(float4*)(dst + 4)  = make_float4(lg[4],  lg[5],  lg[6],  lg[7]);
    *(float4*)(dst + 8)  = make_float4(lg[8],  lg[9],  lg[10], lg[11]);
    *(float4*)(dst + 12) = make_float4(lg[12], lg[13], lg[14], lg[15]);
    out[OFF_ENT + (tg - 1) * 16 + i] = ent;
  }
}

__launch_bounds__(256, 2)
__global__ void k_mlp(const float* __restrict__ s_array, const float* __restrict__ a_array,
                      const float* __restrict__ pW1, const float* __restrict__ pb1,
                      const float* __restrict__ pW2, const float* __restrict__ pb2,
                      const float* __restrict__ pW3, const float* __restrict__ pb3,
                      const float* __restrict__ oW1, const float* __restrict__ ob1,
                      const float* __restrict__ oW2, const float* __restrict__ ob2,
                      const float* __restrict__ oW3, const float* __restrict__ ob3,
                      const float* __restrict__ als,
                      float* out, float* ws)
{
  __shared__ float Xs[32 * 68];
  __shared__ float Hs[32 * 260];
  __shared__ float tr0[16];
  const int tid = threadIdx.x;
  const int i = tid & 15;
  const int rh = tid >> 4;
  const size_t row0 = (size_t)blockIdx.x * 32;

  { // stage X (32 rows x 64) into LDS, coalesced
    const float4* src = (const float4*)(s_array + row0 * 64);
    for (int f = tid; f < 512; f += 256) {
      float4 v = src[f];
      int r = f >> 4, cc = (f & 15) * 4;
      *(float4*)&Xs[r * 68 + cc] = v;
    }
  }
  __syncthreads();

  float acc0[16], acc1[16];

  // ===== option net =====
  gemm_16col<64, 68>(Xs, oW1, 256, ob1, i * 16, rh, acc0, acc1);
  store_relu16(Hs, rh, i * 16, acc0);
  store_relu16(Hs, rh + 16, i * 16, acc1);
  __syncthreads();
  gemm_16col<256, 260>(Hs, oW2, 256, ob2, i * 16, rh, acc0, acc1);
  __syncthreads();
  store_relu16(Hs, rh, i * 16, acc0);
  store_relu16(Hs, rh + 16, i * 16, acc1);
  __syncthreads();
  gemm_16col<256, 260>(Hs, oW3, 272, ob3, i * 16, rh, acc0, acc1);
  softmax_ep(acc0, row0 + rh, i, out);
  softmax_ep(acc1, row0 + rh + 16, i, out);
  // global row 0 needs the extra (i==16) softmax group for log_tr0
  if (blockIdx.x == 0 && tid < 16) {
    float acc = ob3[256 + tid];
    for (int k = 0; k < 256; k++) acc = fmaf(Hs[k], oW3[(size_t)k * 272 + 256 + tid], acc);
    tr0[tid] = acc;
  }
  __syncthreads();
  if (blockIdx.x == 0 && tid == 0) {
    float m = NEGINF;
    for (int j = 0; j < 16; j++) m = fmaxf(m, tr0[j]);
    float s = 0.f;
    for (int j = 0; j < 16; j++) s += __expf(tr0[j] - m);
    float L = m + __logf(s);
    for (int j = 0; j < 16; j++) ws[WS_TR0 + j] = tr0[j] - L;
  }

  // ===== policy net =====
  gemm_16col<64, 68>(Xs, pW1, 256, pb1, i * 16, rh, acc0, acc1);
  store_relu16(Hs, rh, i * 16, acc0);
  store_relu16(Hs, rh + 16, i * 16, acc1);
  __syncthreads();
  gemm_16col<256, 260>(Hs, pW2, 256, pb2, i * 16, rh, acc0, acc1);
  __syncthreads();
  store_relu16(Hs, rh, i * 16, acc0);
  store_relu16(Hs, rh + 16, i * 16, acc1);
  __syncthreads();
  float pc0[8], pc1[8];
  gemm_8col<256, 260>(Hs, pW3, 128, pb3, i * 8, rh, pc0, pc1);

  // gaussian log-prob epilogue
  float istd[8];
  float Kc = -8.0f * 0.91893853320467274f;
#pragma unroll
  for (int a = 0; a < 8; a++) {
    float l = -5.0f + 3.5f * (tanhf(als[a]) + 1.0f);
    istd[a] = __expf(-l);
    Kc -= l;
  }
  {
    size_t tg = row0 + rh;
    const float* at = a_array + tg * 8;
    float q = 0.f;
#pragma unroll
    for (int a = 0; a < 8; a++) {
      float mn = fminf(10.f, fmaxf(-10.f, pc0[a]));
      float z = (at[a] - mn) * istd[a];
      q = fmaf(z, z, q);
    }
    out[OFF_LPI + tg * 16 + i] = -0.5f * q + Kc;
  }
  {
    size_t tg = row0 + rh + 16;
    const float* at = a_array + tg * 8;
    float q = 0.f;
#pragma unroll
    for (int a = 0; a < 8; a++) {
      float mn = fminf(10.f, fmaxf(-10.f, pc1[a]));
      float z = (at[a] - mn) * istd[a];
      q = fmaf(z, z, q);
    }
    out[OFF_LPI + tg * 16 + i] = -0.5f * q + Kc;
  }
}

// ------------------------------------------------- K2: per-chunk log-matmul ---

__launch_bounds__(256, 4)
__global__ void k_compose(const float* __restrict__ out, float* __restrict__ ws)
{
  __shared__ float M[2][16 * 17];
  __shared__ float As[16 * 17];
  __shared__ float Ls[16];
  const int tid = threadIdx.x;
  const int i = tid >> 4, k = tid & 15;
  const int c = blockIdx.x;
  long long e0 = (long long)c * CS;
  long long e1 = e0 + CS; if (e1 > NSTEP) e1 = NSTEP;
  float last = (i == k) ? 0.f : NEGINF;
  M[0][i * 17 + k] = last;
  int cur = 0;
  for (long long e = e0; e < e1; e++) {
    As[(tid >> 4) * 17 + (tid & 15)] = out[OFF_LTR + (size_t)e * 256 + tid];
    if (tid < 16) Ls[tid] = out[OFF_LPI + (size_t)(e + 1) * 16 + tid];
    __syncthreads();
    float v[16]; float m = NEGINF;
#pragma unroll
    for (int j = 0; j < 16; j++) { v[j] = M[cur][i * 17 + j] + As[j * 17 + k]; m = fmaxf(m, v[j]); }
    float s = 0.f;
#pragma unroll
    for (int j = 0; j < 16; j++) s += __expf(v[j] - m);
    last = m + __logf(s) + Ls[k];
    __syncthreads();
    M[cur ^ 1][i * 17 + k] = last;
    cur ^= 1;
  }
  ws[WS_M + (size_t)c * 256 + tid] = last;
}

// -------------------------------- K3/K4: group-level matrix prefix & suffix ---

__launch_bounds__(256, 4)
__global__ void k_scan_mats(const float* __restrict__ src, float* __restrict__ preDst,
                            float* __restrict__ sufDst, float* __restrict__ totDst)
{
  __shared__ float Cur[16 * 17];
  const int tid = threadIdx.x, i = tid >> 4, k = tid & 15;
  const int g = blockIdx.x;
  const float* S = src + (size_t)g * 32 * 256;
  const float id = (i == k) ? 0.f : NEGINF;

  Cur[i * 17 + k] = id;
  __syncthreads();
  for (int r = 0; r < 32; r++) {
    preDst[((size_t)g * 32 + r) * 256 + tid] = Cur[i * 17 + k];
    const float* R = S + r * 256;
    float v[16]; float m = NEGINF;
#pragma unroll
    for (int j = 0; j < 16; j++) { v[j] = Cur[i * 17 + j] + R[j * 16 + k]; m = fmaxf(m, v[j]); }
    float s = 0.f;
#pragma unroll
    for (int j = 0; j < 16; j++) s += __expf(v[j] - m);
    float res = m + __logf(s);
    __syncthreads();
    Cur[i * 17 + k] = res;
    __syncthreads();
  }
  if (totDst) totDst[(size_t)g * 256 + tid] = Cur[i * 17 + k];
  __syncthreads();
  Cur[i * 17 + k] = id;
  __syncthreads();
  for (int r = 31; r >= 0; r--) {
    sufDst[((size_t)g * 32 + r) * 256 + tid] = Cur[i * 17 + k];
    const float* L = S + r * 256;
    float v[16]; float m = NEGINF;
#pragma unroll
    for (int j = 0; j < 16; j++) { v[j] = L[i * 16 + j] + Cur[j * 17 + k]; m = fmaxf(m, v[j]); }
    float s = 0.f;
#pragma unroll
    for (int j = 0; j < 16; j++) s += __expf(v[j] - m);
    float res = m + __logf(s);
    __syncthreads();
    Cur[i * 17 + k] = res;
    __syncthreads();
  }
}

// ------------------------- K5: chunk-level exclusive prefix/suffix matrices ---

__launch_bounds__(256, 4)
__global__ void k_combine(float* ws)
{
  const int tid = threadIdx.x, i = tid >> 4, k = tid & 15;
  const int c = blockIdx.x, g = c >> 5;
  {
    const float* GP = ws + WS_GP + (size_t)g * 256;
    const float* LP = ws + WS_LP + (size_t)c * 256;
    float v[16]; float m = NEGINF;
#pragma unroll
    for (int j = 0; j < 16; j++) { v[j] = GP[i * 16 + j] + LP[j * 16 + k]; m = fmaxf(m, v[j]); }
    float s = 0.f;
#pragma unroll
    for (int j = 0; j < 16; j++) s += __expf(v[j] - m);
    ws[WS_PREF + (size_t)c * 256 + tid] = m + __logf(s);
  }
  {
    const float* LSu = ws + WS_LS + (size_t)c * 256;
    const float* GSu = ws + WS_GSU + (size_t)g * 256;
    float v[16]; float m = NEGINF;
#pragma unroll
    for (int j = 0; j < 16; j++) { v[j] = LSu[i * 16 + j] + GSu[j * 16 + k]; m = fmaxf(m, v[j]); }
    float s = 0.f;
#pragma unroll
    for (int j = 0; j < 16; j++) s += __expf(v[j] - m);
    ws[WS_SUF + (size_t)c * 256 + tid] = m + __logf(s);
  }
}

// --------------------------------------------------------- K6: chunk replay ---

__device__ __forceinline__ void lse_combine(float& m, float& s, int mask)
{
  float m2 = __shfl_xor(m, mask, 64);
  float s2 = __shfl_xor(s, mask, 64);
  float M_ = fmaxf(m, m2);
  s = s * __expf(m - M_) + s2 * __expf(m2 - M_);
  m = M_;
}

__launch_bounds__(128, 4)
__global__ void k_replay(const float* __restrict__ ws, float* out)
{
  const int c = blockIdx.x;
  long long e0 = (long long)c * CS;
  long long e1 = e0 + CS; if (e1 > NSTEP) e1 = NSTEP;
  const int lane = threadIdx.x & 63;
  const int wv = threadIdx.x >> 6;
  const int x = lane & 15;  // output index (j for alpha, i for beta)
  const int q = lane >> 4;  // quarter: reduces 4 of the 16 contraction terms

  if (wv == 0) {
    // ---------------- alpha (forward) ----------------
    if (c == 0 && lane < 16)
      out[OFF_A + lane] = ws[WS_TR0 + lane] + out[OFF_LPI + lane];
    const float* P = ws + WS_PREF + (size_t)c * 256;
    float v4[4]; float m = NEGINF;
#pragma unroll
    for (int t2 = 0; t2 < 4; t2++) {
      int i2 = 4 * q + t2;
      float a0i = ws[WS_TR0 + i2] + out[OFF_LPI + i2];
      float vv = a0i + P[i2 * 16 + x];
      v4[t2] = vv; m = fmaxf(m, vv);
    }
    float s = 0.f;
#pragma unroll
    for (int t2 = 0; t2 < 4; t2++) s += __expf(v4[t2] - m);
    lse_combine(m, s, 16); lse_combine(m, s, 32);
    float cv = m + __logf(s);
    float vq[4];
#pragma unroll
    for (int t2 = 0; t2 < 4; t2++) vq[t2] = __shfl(cv, q * 4 + t2, 64);
    for (long long e = e0; e < e1; e++) {
      long long t = e + 1;
      float w4[4]; float m2 = NEGINF;
#pragma unroll
      for (int t2 = 0; t2 < 4; t2++) {
        float tr = out[OFF_LTR + (size_t)e * 256 + (size_t)(4 * q + t2) * 16 + x];
        float vvv = vq[t2] + tr;
        w4[t2] = vvv; m2 = fmaxf(m2, vvv);
      }
      float s2 = 0.f;
#pragma unroll
      for (int t2 = 0; t2 < 4; t2++) s2 += __expf(w4[t2] - m2);
      lse_combine(m2, s2, 16); lse_combine(m2, s2, 32);
      float nv = m2 + __logf(s2) + out[OFF_LPI + (size_t)t * 16 + x];
      if (lane < 16) out[OFF_A + (size_t)t * 16 + x] = nv;
#pragma unroll
      for (int t2 = 0; t2 < 4; t2++) vq[t2] = __shfl(nv, q * 4 + t2, 64);
    }
  } else {
    // ---------------- beta (backward) ----------------
    if (c == NC - 1 && lane < 16) out[OFF_B + (size_t)(T_N - 1) * 16 + lane] = 0.f;
    const float* Sf = ws + WS_SUF + (size_t)c * 256;
    float v4[4]; float m = NEGINF;
#pragma unroll
    for (int t2 = 0; t2 < 4; t2++) {
      float vv = Sf[x * 16 + 4 * q + t2];
      v4[t2] = vv; m = fmaxf(m, vv);
    }
    float s = 0.f;
#pragma unroll
    for (int t2 = 0; t2 < 4; t2++) s += __expf(v4[t2] - m);
    lse_combine(m, s, 16); lse_combine(m, s, 32);
    float u = m + __logf(s);
    float uq[4];
#pragma unroll
    for (int t2 = 0; t2 < 4; t2++) uq[t2] = __shfl(u, q * 4 + t2, 64);
    for (long long e = e1 - 1; e >= e0; e--) {
      float w4[4]; float m2 = NEGINF;
#pragma unroll
      for (int t2 = 0; t2 < 4; t2++) {
        int j2 = 4 * q + t2;
        float tr = out[OFF_LTR + (size_t)e * 256 + (size_t)x * 16 + j2];
        float lp = out[OFF_LPI + (size_t)(e + 1) * 16 + j2];
        float vvv = tr + lp + uq[t2];
        w4[t2] = vvv; m2 = fmaxf(m2, vvv);
      }
      float s2 = 0.f;
#pragma unroll
      for (int t2 = 0; t2 < 4; t2++) s2 += __expf(w4[t2] - m2);
      lse_combine(m2, s2, 16); lse_combine(m2, s2, 32);
      float b = m2 + __logf(s2);
      if (lane < 16) out[OFF_B + (size_t)e * 16 + x] = b;
#pragma unroll
      for (int t2 = 0; t2 < 4; t2++) uq[t2] = __shfl(b, q * 4 + t2, 64);
    }
  }
}

// ------------------------------------------------------------------- launch ---

extern "C" void kernel_launch(void* const* d_in, const int* in_sizes, int n_in,
                              void* d_out, int out_size, void* d_ws, size_t ws_size,
                              hipStream_t stream)
{
  const float* s_array = (const float*)d_in[0];
  const float* a_array = (const float*)d_in[1];
  const float* pW1 = (const float*)d_in[2];
  const float* pb1 = (const float*)d_in[3];
  const float* pW2 = (const float*)d_in[4];
  const float* pb2 = (const float*)d_in[5];
  const float* pW3 = (const float*)d_in[6];
  const float* pb3 = (const float*)d_in[7];
  const float* oW1 = (const float*)d_in[8];
  const float* ob1 = (const float*)d_in[9];
  const float* oW2 = (const float*)d_in[10];
  const float* ob2 = (const float*)d_in[11];
  const float* oW3 = (const float*)d_in[12];
  const float* ob3 = (const float*)d_in[13];
  const float* als = (const float*)d_in[14];
  float* out = (float*)d_out;
  float* ws  = (float*)d_ws;

  hipLaunchKernelGGL(k_mlp, dim3(T_N / 32), dim3(256), 0, stream,
                     s_array, a_array, pW1, pb1, pW2, pb2, pW3, pb3,
                     oW1, ob1, oW2, ob2, oW3, ob3, als, out, ws);
  hipLaunchKernelGGL(k_compose, dim3(NC), dim3(256), 0, stream, out, ws);
  hipLaunchKernelGGL(k_scan_mats, dim3(NG), dim3(256), 0, stream,
                     ws + WS_M, ws + WS_LP, ws + WS_LS, ws + WS_GT);
  hipLaunchKernelGGL(k_scan_mats, dim3(1), dim3(256), 0, stream,
                     ws + WS_GT, ws + WS_GP, ws + WS_GSU, (float*)nullptr);
  hipLaunchKernelGGL(k_combine, dim3(NC), dim3(256), 0, stream, ws);
  hipLaunchKernelGGL(k_replay, dim3(NC), dim3(128), 0, stream, ws, out);
}

// Round 2
// 1638.564 us; speedup vs baseline: 4.6430x; 4.6430x over previous
//
#include <hip/hip_runtime.h>
#include <hip/hip_bf16.h>
#include <math.h>

#define T_N   262144
#define NSTEP (T_N - 1)   // 262143 scan steps
#define CS    256         // chunk size
#define NC    1024        // number of chunks (NC*CS >= NSTEP)
#define NG    32          // groups of chunks (NC/32)

// output layout (floats): log_alpha(T,16) log_beta(T,16) log_trs(T-1,256) log_pis(T,16) entropy(T-1,16)
#define OFF_A   ((size_t)0)
#define OFF_B   ((size_t)4194304)
#define OFF_LTR ((size_t)8388608)
#define OFF_LPI ((size_t)75497216)
#define OFF_ENT ((size_t)79691520)

// workspace layout (floats)
#define WS_TR0  ((size_t)0)
#define WS_M    ((size_t)64)
#define WS_LP   (WS_M  + (size_t)NC*256)
#define WS_LS   (WS_LP + (size_t)NC*256)
#define WS_GT   (WS_LS + (size_t)NC*256)
#define WS_GP   (WS_GT + (size_t)NG*256)
#define WS_GSU  (WS_GP + (size_t)NG*256)
#define WS_PREF (WS_GSU + (size_t)NG*256)
#define WS_SUF  (WS_PREF + (size_t)NC*256)
#define WS_WP   (WS_SUF  + (size_t)NC*256)   // packed bf16 weights start here (as ushort)

// packed-weight offsets (ushort units)
#define O_pW1h 0
#define O_pW1l 16384
#define O_pW2h 32768
#define O_pW2l 98304
#define O_pW3h 163840
#define O_pW3l 196608
#define O_oW1h 229376
#define O_oW1l 245760
#define O_oW2h 262144
#define O_oW2l 327680
#define O_oW3h 393216
#define O_oW3l 462848

#define NEGINF (-1e30f)

typedef unsigned short ushort_t;
typedef short s8v __attribute__((ext_vector_type(8)));
typedef float f4v __attribute__((ext_vector_type(4)));

__device__ __forceinline__ ushort_t f2bf_rn(float f) {
  __hip_bfloat16 h = __float2bfloat16(f);
  union { __hip_bfloat16 b; ushort_t u; } cv; cv.b = h; return cv.u;
}
__device__ __forceinline__ float us2f(ushort_t u) {
  return __uint_as_float(((unsigned)u) << 16);
}
__device__ __forceinline__ void split_bf(float x, ushort_t& h, ushort_t& lo) {
  unsigned u = __float_as_uint(x);
  h = (ushort_t)(u >> 16);
  lo = f2bf_rn(x - __uint_as_float(u & 0xffff0000u));
}

// ----------------------------------------------------------- weight packing ---
// layout: idx = ((ks*NT + nt)*64 + lane)*8 + j  maps  B[k=ks*32+(lane>>4)*8+j][n=nt*16+(lane&15)]
__global__ void k_pack(const float* __restrict__ W, int KN, int NT, int N,
                       ushort_t* __restrict__ dh, ushort_t* __restrict__ dl)
{
  int idx = blockIdx.x * 256 + threadIdx.x;
  if (idx >= KN) return;
  int j  = idx & 7;
  int l  = (idx >> 3) & 63;
  int t2 = idx >> 9;
  int nt = t2 % NT;
  int ks = t2 / NT;
  int k = ks * 32 + (l >> 4) * 8 + j;
  int n = nt * 16 + (l & 15);
  float x = W[(size_t)k * N + n];
  unsigned u = __float_as_uint(x);
  dh[idx] = (ushort_t)(u >> 16);
  dl[idx] = f2bf_rn(x - __uint_as_float(u & 0xffff0000u));
}

// ---------------------------------------------------------------- K1: MLPs ---

#define LDX 72
#define LDH 264

template<int KS, int NTC>
__device__ __forceinline__ void run_layer(const ushort_t* Ah, const ushort_t* Al, int lda,
    const ushort_t* __restrict__ Bh, const ushort_t* __restrict__ Bl, int ntt, int nt0,
    const float* __restrict__ bias, int lane, f4v (&acc)[2][NTC])
{
#pragma unroll
  for (int mt = 0; mt < 2; mt++)
#pragma unroll
    for (int nt = 0; nt < NTC; nt++) {
      float b = bias[(nt0 + nt) * 16 + (lane & 15)];
      acc[mt][nt] = (f4v){b, b, b, b};
    }
  for (int ks = 0; ks < KS; ks++) {
    s8v ah[2], al[2];
#pragma unroll
    for (int mt = 0; mt < 2; mt++) {
      const ushort_t* p = Ah + (size_t)(mt * 16 + (lane & 15)) * lda + ks * 32 + (lane >> 4) * 8;
      ah[mt] = *(const s8v*)p;
      const ushort_t* q = Al + (size_t)(mt * 16 + (lane & 15)) * lda + ks * 32 + (lane >> 4) * 8;
      al[mt] = *(const s8v*)q;
    }
#pragma unroll
    for (int nt = 0; nt < NTC; nt++) {
      size_t bo = ((size_t)(ks * ntt + nt0 + nt) * 64 + lane) * 8;
      s8v bh = *(const s8v*)(Bh + bo);
      s8v bl = *(const s8v*)(Bl + bo);
#pragma unroll
      for (int mt = 0; mt < 2; mt++) {
        acc[mt][nt] = __builtin_amdgcn_mfma_f32_16x16x32_bf16(ah[mt], bh, acc[mt][nt], 0, 0, 0);
        acc[mt][nt] = __builtin_amdgcn_mfma_f32_16x16x32_bf16(al[mt], bh, acc[mt][nt], 0, 0, 0);
        acc[mt][nt] = __builtin_amdgcn_mfma_f32_16x16x32_bf16(ah[mt], bl, acc[mt][nt], 0, 0, 0);
      }
    }
  }
}

__device__ __forceinline__ void store_act(f4v (&acc)[2][4], int nt0, int lane,
                                          ushort_t* Hh, ushort_t* Hl)
{
#pragma unroll
  for (int mt = 0; mt < 2; mt++)
#pragma unroll
    for (int nt = 0; nt < 4; nt++)
#pragma unroll
      for (int r = 0; r < 4; r++) {
        float v = fmaxf(acc[mt][nt][r], 0.f);
        ushort_t h, lo; split_bf(v, h, lo);
        int row = mt * 16 + (lane >> 4) * 4 + r;
        int n = (nt0 + nt) * 16 + (lane & 15);
        Hh[row * LDH + n] = h;
        Hl[row * LDH + n] = lo;
      }
}

__launch_bounds__(256, 3)
__global__ void k_mlp2(const float* __restrict__ s_array, const float* __restrict__ a_array,
                       const float* __restrict__ pb1, const float* __restrict__ pb2,
                       const float* __restrict__ pb3, const float* __restrict__ ob1,
                       const float* __restrict__ ob2, const float* __restrict__ ob3,
                       const float* __restrict__ oW3, const float* __restrict__ als,
                       const ushort_t* __restrict__ wp, float* out, float* ws)
{
  __shared__ ushort_t Xh[32 * LDX], Xl[32 * LDX];
  __shared__ ushort_t Hh[32 * LDH], Hl[32 * LDH];
  __shared__ float tr0s[16];
  const int tid = threadIdx.x;
  const int lane = tid & 63;
  const int w = tid >> 6;
  const size_t row0 = (size_t)blockIdx.x * 32;

  { // stage X (32 rows x 64) into LDS split-bf16, A-frag friendly
    const float4* src = (const float4*)(s_array + row0 * 64);
    for (int f = tid; f < 512; f += 256) {
      float4 v = src[f];
      int r = f >> 4, c = (f & 15) * 4;
      ushort_t h0, l0, h1, l1, h2, l2, h3, l3;
      split_bf(v.x, h0, l0); split_bf(v.y, h1, l1);
      split_bf(v.z, h2, l2); split_bf(v.w, h3, l3);
      ushort4 hh = make_ushort4(h0, h1, h2, h3);
      ushort4 ll = make_ushort4(l0, l1, l2, l3);
      *(ushort4*)&Xh[r * LDX + c] = hh;
      *(ushort4*)&Xl[r * LDX + c] = ll;
    }
  }
  __syncthreads();

  f4v acc[2][4];

  // ===== option net =====
  run_layer<2, 4>(Xh, Xl, LDX, wp + O_oW1h, wp + O_oW1l, 16, w * 4, ob1, lane, acc);
  store_act(acc, w * 4, lane, Hh, Hl);
  __syncthreads();
  run_layer<8, 4>(Hh, Hl, LDH, wp + O_oW2h, wp + O_oW2l, 16, w * 4, ob2, lane, acc);
  __syncthreads();
  store_act(acc, w * 4, lane, Hh, Hl);
  __syncthreads();
  run_layer<8, 4>(Hh, Hl, LDH, wp + O_oW3h, wp + O_oW3l, 17, w * 4, ob3, lane, acc);

  // log-softmax + entropy epilogue (groups == 16-col tiles)
#pragma unroll
  for (int mt = 0; mt < 2; mt++)
#pragma unroll
    for (int nt = 0; nt < 4; nt++) {
      int g = w * 4 + nt;
      int col = lane & 15;
#pragma unroll
      for (int r = 0; r < 4; r++) {
        size_t t = row0 + mt * 16 + (lane >> 4) * 4 + r;
        float x = acc[mt][nt][r];
        float m = x;
        m = fmaxf(m, __shfl_xor(m, 1, 64));
        m = fmaxf(m, __shfl_xor(m, 2, 64));
        m = fmaxf(m, __shfl_xor(m, 4, 64));
        m = fmaxf(m, __shfl_xor(m, 8, 64));
        float s = __expf(x - m);
        s += __shfl_xor(s, 1, 64);
        s += __shfl_xor(s, 2, 64);
        s += __shfl_xor(s, 4, 64);
        s += __shfl_xor(s, 8, 64);
        float L = m + __logf(s);
        float v = x - L;
        float e = -v * __expf(v);
        e += __shfl_xor(e, 1, 64);
        e += __shfl_xor(e, 2, 64);
        e += __shfl_xor(e, 4, 64);
        e += __shfl_xor(e, 8, 64);
        if (t >= 1) {
          out[OFF_LTR + (t - 1) * 256 + (size_t)g * 16 + col] = v;
          if (col == 0) out[OFF_ENT + (t - 1) * 16 + g] = e;
        }
      }
    }

  // log_tr0: row 0's 17th group (block 0 only); H still holds option act2
  if (blockIdx.x == 0 && tid < 16) {
    float a = ob3[256 + tid];
    for (int k2 = 0; k2 < 256; k2++) {
      float hv = us2f(Hh[k2]) + us2f(Hl[k2]);
      a = fmaf(hv, oW3[(size_t)k2 * 272 + 256 + tid], a);
    }
    tr0s[tid] = a;
  }
  __syncthreads();   // also guards H reads (option L3) vs policy L1 writes
  if (blockIdx.x == 0 && tid == 0) {
    float m = NEGINF;
    for (int j = 0; j < 16; j++) m = fmaxf(m, tr0s[j]);
    float s = 0.f;
    for (int j = 0; j < 16; j++) s += __expf(tr0s[j] - m);
    float L = m + __logf(s);
    for (int j = 0; j < 16; j++) ws[WS_TR0 + j] = tr0s[j] - L;
  }

  // ===== policy net =====
  run_layer<2, 4>(Xh, Xl, LDX, wp + O_pW1h, wp + O_pW1l, 16, w * 4, pb1, lane, acc);
  store_act(acc, w * 4, lane, Hh, Hl);
  __syncthreads();
  run_layer<8, 4>(Hh, Hl, LDH, wp + O_pW2h, wp + O_pW2l, 16, w * 4, pb2, lane, acc);
  __syncthreads();
  store_act(acc, w * 4, lane, Hh, Hl);
  __syncthreads();
  f4v pacc[2][2];
  run_layer<8, 2>(Hh, Hl, LDH, wp + O_pW3h, wp + O_pW3l, 8, w * 2, pb3, lane, pacc);

  // gaussian log-prob epilogue
  float istd[8];
  float Kc = -8.0f * 0.91893853320467274f;
#pragma unroll
  for (int a = 0; a < 8; a++) {
    float l = -5.0f + 3.5f * (tanhf(als[a]) + 1.0f);
    istd[a] = __expf(-l);
    Kc -= l;
  }
  int aIdx = lane & 7;
#pragma unroll
  for (int mt = 0; mt < 2; mt++)
#pragma unroll
    for (int nt = 0; nt < 2; nt++) {
      int col = (w * 2 + nt) * 16 + (lane & 15);
      int c = col >> 3;
#pragma unroll
      for (int r = 0; r < 4; r++) {
        size_t t = row0 + mt * 16 + (lane >> 4) * 4 + r;
        float mean = fminf(10.f, fmaxf(-10.f, pacc[mt][nt][r]));
        float av = a_array[t * 8 + aIdx];
        float z = (av - mean) * istd[aIdx];
        float q = z * z;
        q += __shfl_xor(q, 1, 64);
        q += __shfl_xor(q, 2, 64);
        q += __shfl_xor(q, 4, 64);
        if ((lane & 7) == 0) out[OFF_LPI + t * 16 + c] = -0.5f * q + Kc;
      }
    }
}

// ------------------------------------------------- K2: per-chunk log-matmul ---

__launch_bounds__(256, 4)
__global__ void k_compose(const float* __restrict__ out, float* __restrict__ ws)
{
  __shared__ float M[2][16 * 17];
  __shared__ float As[16 * 17];
  __shared__ float Ls[16];
  const int tid = threadIdx.x;
  const int i = tid >> 4, k = tid & 15;
  const int c = blockIdx.x;
  long long e0 = (long long)c * CS;
  long long e1 = e0 + CS; if (e1 > NSTEP) e1 = NSTEP;
  float last = (i == k) ? 0.f : NEGINF;
  M[0][i * 17 + k] = last;
  int cur = 0;
  for (long long e = e0; e < e1; e++) {
    As[(tid >> 4) * 17 + (tid & 15)] = out[OFF_LTR + (size_t)e * 256 + tid];
    if (tid < 16) Ls[tid] = out[OFF_LPI + (size_t)(e + 1) * 16 + tid];
    __syncthreads();
    float v[16]; float m = NEGINF;
#pragma unroll
    for (int j = 0; j < 16; j++) { v[j] = M[cur][i * 17 + j] + As[j * 17 + k]; m = fmaxf(m, v[j]); }
    float s = 0.f;
#pragma unroll
    for (int j = 0; j < 16; j++) s += __expf(v[j] - m);
    last = m + __logf(s) + Ls[k];
    __syncthreads();
    M[cur ^ 1][i * 17 + k] = last;
    cur ^= 1;
  }
  ws[WS_M + (size_t)c * 256 + tid] = last;
}

// -------------------------------- K3/K4: group-level matrix prefix & suffix ---

__launch_bounds__(256, 4)
__global__ void k_scan_mats(const float* __restrict__ src, float* __restrict__ preDst,
                            float* __restrict__ sufDst, float* __restrict__ totDst)
{
  __shared__ float Cur[16 * 17];
  const int tid = threadIdx.x, i = tid >> 4, k = tid & 15;
  const int g = blockIdx.x;
  const float* S = src + (size_t)g * 32 * 256;
  const float id = (i == k) ? 0.f : NEGINF;

  Cur[i * 17 + k] = id;
  __syncthreads();
  for (int r = 0; r < 32; r++) {
    preDst[((size_t)g * 32 + r) * 256 + tid] = Cur[i * 17 + k];
    const float* R = S + r * 256;
    float v[16]; float m = NEGINF;
#pragma unroll
    for (int j = 0; j < 16; j++) { v[j] = Cur[i * 17 + j] + R[j * 16 + k]; m = fmaxf(m, v[j]); }
    float s = 0.f;
#pragma unroll
    for (int j = 0; j < 16; j++) s += __expf(v[j] - m);
    float res = m + __logf(s);
    __syncthreads();
    Cur[i * 17 + k] = res;
    __syncthreads();
  }
  if (totDst) totDst[(size_t)g * 256 + tid] = Cur[i * 17 + k];
  __syncthreads();
  Cur[i * 17 + k] = id;
  __syncthreads();
  for (int r = 31; r >= 0; r--) {
    sufDst[((size_t)g * 32 + r) * 256 + tid] = Cur[i * 17 + k];
    const float* L = S + r * 256;
    float v[16]; float m = NEGINF;
#pragma unroll
    for (int j = 0; j < 16; j++) { v[j] = L[i * 16 + j] + Cur[j * 17 + k]; m = fmaxf(m, v[j]); }
    float s = 0.f;
#pragma unroll
    for (int j = 0; j < 16; j++) s += __expf(v[j] - m);
    float res = m + __logf(s);
    __syncthreads();
    Cur[i * 17 + k] = res;
    __syncthreads();
  }
}

// ------------------------- K5: chunk-level exclusive prefix/suffix matrices ---

__launch_bounds__(256, 4)
__global__ void k_combine(float* ws)
{
  const int tid = threadIdx.x, i = tid >> 4, k = tid & 15;
  const int c = blockIdx.x, g = c >> 5;
  {
    const float* GP = ws + WS_GP + (size_t)g * 256;
    const float* LP = ws + WS_LP + (size_t)c * 256;
    float v[16]; float m = NEGINF;
#pragma unroll
    for (int j = 0; j < 16; j++) { v[j] = GP[i * 16 + j] + LP[j * 16 + k]; m = fmaxf(m, v[j]); }
    float s = 0.f;
#pragma unroll
    for (int j = 0; j < 16; j++) s += __expf(v[j] - m);
    ws[WS_PREF + (size_t)c * 256 + tid] = m + __logf(s);
  }
  {
    const float* LSu = ws + WS_LS + (size_t)c * 256;
    const float* GSu = ws + WS_GSU + (size_t)g * 256;
    float v[16]; float m = NEGINF;
#pragma unroll
    for (int j = 0; j < 16; j++) { v[j] = LSu[i * 16 + j] + GSu[j * 16 + k]; m = fmaxf(m, v[j]); }
    float s = 0.f;
#pragma unroll
    for (int j = 0; j < 16; j++) s += __expf(v[j] - m);
    ws[WS_SUF + (size_t)c * 256 + tid] = m + __logf(s);
  }
}

// --------------------------------------------------------- K6: chunk replay ---

__device__ __forceinline__ void lse_combine(float& m, float& s, int mask)
{
  float m2 = __shfl_xor(m, mask, 64);
  float s2 = __shfl_xor(s, mask, 64);
  float M_ = fmaxf(m, m2);
  s = s * __expf(m - M_) + s2 * __expf(m2 - M_);
  m = M_;
}

__launch_bounds__(128, 4)
__global__ void k_replay(const float* __restrict__ ws, float* out)
{
  const int c = blockIdx.x;
  long long e0 = (long long)c * CS;
  long long e1 = e0 + CS; if (e1 > NSTEP) e1 = NSTEP;
  const int lane = threadIdx.x & 63;
  const int wv = threadIdx.x >> 6;
  const int x = lane & 15;  // output index (j for alpha, i for beta)
  const int q = lane >> 4;  // quarter: reduces 4 of the 16 contraction terms

  if (wv == 0) {
    // ---------------- alpha (forward) ----------------
    if (c == 0 && lane < 16)
      out[OFF_A + lane] = ws[WS_TR0 + lane] + out[OFF_LPI + lane];
    const float* P = ws + WS_PREF + (size_t)c * 256;
    float v4[4]; float m = NEGINF;
#pragma unroll
    for (int t2 = 0; t2 < 4; t2++) {
      int i2 = 4 * q + t2;
      float a0i = ws[WS_TR0 + i2] + out[OFF_LPI + i2];
      float vv = a0i + P[i2 * 16 + x];
      v4[t2] = vv; m = fmaxf(m, vv);
    }
    float s = 0.f;
#pragma unroll
    for (int t2 = 0; t2 < 4; t2++) s += __expf(v4[t2] - m);
    lse_combine(m, s, 16); lse_combine(m, s, 32);
    float cv = m + __logf(s);
    float vq[4];
#pragma unroll
    for (int t2 = 0; t2 < 4; t2++) vq[t2] = __shfl(cv, q * 4 + t2, 64);
    for (long long e = e0; e < e1; e++) {
      long long t = e + 1;
      float w4[4]; float m2 = NEGINF;
#pragma unroll
      for (int t2 = 0; t2 < 4; t2++) {
        float tr = out[OFF_LTR + (size_t)e * 256 + (size_t)(4 * q + t2) * 16 + x];
        float vvv = vq[t2] + tr;
        w4[t2] = vvv; m2 = fmaxf(m2, vvv);
      }
      float s2 = 0.f;
#pragma unroll
      for (int t2 = 0; t2 < 4; t2++) s2 += __expf(w4[t2] - m2);
      lse_combine(m2, s2, 16); lse_combine(m2, s2, 32);
      float nv = m2 + __logf(s2) + out[OFF_LPI + (size_t)t * 16 + x];
      if (lane < 16) out[OFF_A + (size_t)t * 16 + x] = nv;
#pragma unroll
      for (int t2 = 0; t2 < 4; t2++) vq[t2] = __shfl(nv, q * 4 + t2, 64);
    }
  } else {
    // ---------------- beta (backward) ----------------
    if (c == NC - 1 && lane < 16) out[OFF_B + (size_t)(T_N - 1) * 16 + lane] = 0.f;
    const float* Sf = ws + WS_SUF + (size_t)c * 256;
    float v4[4]; float m = NEGINF;
#pragma unroll
    for (int t2 = 0; t2 < 4; t2++) {
      float vv = Sf[x * 16 + 4 * q + t2];
      v4[t2] = vv; m = fmaxf(m, vv);
    }
    float s = 0.f;
#pragma unroll
    for (int t2 = 0; t2 < 4; t2++) s += __expf(v4[t2] - m);
    lse_combine(m, s, 16); lse_combine(m, s, 32);
    float u = m + __logf(s);
    float uq[4];
#pragma unroll
    for (int t2 = 0; t2 < 4; t2++) uq[t2] = __shfl(u, q * 4 + t2, 64);
    for (long long e = e1 - 1; e >= e0; e--) {
      float w4[4]; float m2 = NEGINF;
#pragma unroll
      for (int t2 = 0; t2 < 4; t2++) {
        int j2 = 4 * q + t2;
        float tr = out[OFF_LTR + (size_t)e * 256 + (size_t)x * 16 + j2];
        float lp = out[OFF_LPI + (size_t)(e + 1) * 16 + j2];
        float vvv = tr + lp + uq[t2];
        w4[t2] = vvv; m2 = fmaxf(m2, vvv);
      }
      float s2 = 0.f;
#pragma unroll
      for (int t2 = 0; t2 < 4; t2++) s2 += __expf(w4[t2] - m2);
      lse_combine(m2, s2, 16); lse_combine(m2, s2, 32);
      float b = m2 + __logf(s2);
      if (lane < 16) out[OFF_B + (size_t)e * 16 + x] = b;
#pragma unroll
      for (int t2 = 0; t2 < 4; t2++) uq[t2] = __shfl(b, q * 4 + t2, 64);
    }
  }
}

// ------------------------------------------------------------------- launch ---

extern "C" void kernel_launch(void* const* d_in, const int* in_sizes, int n_in,
                              void* d_out, int out_size, void* d_ws, size_t ws_size,
                              hipStream_t stream)
{
  const float* s_array = (const float*)d_in[0];
  const float* a_array = (const float*)d_in[1];
  const float* pW1 = (const float*)d_in[2];
  const float* pb1 = (const float*)d_in[3];
  const float* pW2 = (const float*)d_in[4];
  const float* pb2 = (const float*)d_in[5];
  const float* pW3 = (const float*)d_in[6];
  const float* pb3 = (const float*)d_in[7];
  const float* oW1 = (const float*)d_in[8];
  const float* ob1 = (const float*)d_in[9];
  const float* oW2 = (const float*)d_in[10];
  const float* ob2 = (const float*)d_in[11];
  const float* oW3 = (const float*)d_in[12];
  const float* ob3 = (const float*)d_in[13];
  const float* als = (const float*)d_in[14];
  float* out = (float*)d_out;
  float* ws  = (float*)d_ws;
  ushort_t* wp = (ushort_t*)(ws + WS_WP);

  hipLaunchKernelGGL(k_pack, dim3(64),  dim3(256), 0, stream, pW1, 16384, 16, 256, wp + O_pW1h, wp + O_pW1l);
  hipLaunchKernelGGL(k_pack, dim3(256), dim3(256), 0, stream, pW2, 65536, 16, 256, wp + O_pW2h, wp + O_pW2l);
  hipLaunchKernelGGL(k_pack, dim3(128), dim3(256), 0, stream, pW3, 32768,  8, 128, wp + O_pW3h, wp + O_pW3l);
  hipLaunchKernelGGL(k_pack, dim3(64),  dim3(256), 0, stream, oW1, 16384, 16, 256, wp + O_oW1h, wp + O_oW1l);
  hipLaunchKernelGGL(k_pack, dim3(256), dim3(256), 0, stream, oW2, 65536, 16, 256, wp + O_oW2h, wp + O_oW2l);
  hipLaunchKernelGGL(k_pack, dim3(272), dim3(256), 0, stream, oW3, 69632, 17, 272, wp + O_oW3h, wp + O_oW3l);

  hipLaunchKernelGGL(k_mlp2, dim3(T_N / 32), dim3(256), 0, stream,
                     s_array, a_array, pb1, pb2, pb3, ob1, ob2, ob3, oW3, als,
                     (const ushort_t*)wp, out, ws);
  hipLaunchKernelGGL(k_compose, dim3(NC), dim3(256), 0, stream, out, ws);
  hipLaunchKernelGGL(k_scan_mats, dim3(NG), dim3(256), 0, stream,
                     ws + WS_M, ws + WS_LP, ws + WS_LS, ws + WS_GT);
  hipLaunchKernelGGL(k_scan_mats, dim3(1), dim3(256), 0, stream,
                     ws + WS_GT, ws + WS_GP, ws + WS_GSU, (float*)nullptr);
  hipLaunchKernelGGL(k_combine, dim3(NC), dim3(256), 0, stream, ws);
  hipLaunchKernelGGL(k_replay, dim3(NC), dim3(128), 0, stream, ws, out);
}